// Round 4
// baseline (1195.636 us; speedup 1.0000x reference)
//
#include <hip/hip_runtime.h>
#include <math.h>

#define B_ 256
#define N_ 200
#define D_ 128
#define H_ 8
#define KD_ 16
#define L_ 3
#define FF_ 512
#define ROWS (B_*N_)          // 51200
#define BND (ROWS*D_)         // 6,553,600

typedef __bf16 bf16x8 __attribute__((ext_vector_type(8)));
typedef float f32x4 __attribute__((ext_vector_type(4)));

__device__ __forceinline__ ushort f2bf(float f) {
  union { float f; unsigned u; } v; v.f = f;
  unsigned r = v.u + 0x7fffu + ((v.u >> 16) & 1u);
  return (ushort)(r >> 16);
}
__device__ __forceinline__ float bf2f(ushort h) {
  union { unsigned u; float f; } v; v.u = ((unsigned)h) << 16; return v.f;
}
__device__ __forceinline__ void split2(float f, ushort& hi, ushort& lo) {
  hi = f2bf(f);
  lo = f2bf(f - bf2f(hi));
}

// ---------------- embed: h = x @ Wemb + bemb -> h fp32 + hi/lo bf16 ----------------
__global__ __launch_bounds__(256) void embed_kernel(const float* __restrict__ x,
    const float* __restrict__ Wemb, const float* __restrict__ bemb,
    float* __restrict__ h, ushort* __restrict__ hhi, ushort* __restrict__ hlo)
{
  int i4 = blockIdx.x * 256 + threadIdx.x;   // ROWS*32 float4s
  int r  = i4 >> 5, c4 = i4 & 31;
  float x0 = x[2*r], x1 = x[2*r + 1];
  const float4 w0 = ((const float4*)Wemb)[c4];
  const float4 w1 = ((const float4*)Wemb)[32 + c4];
  const float4 bb = ((const float4*)bemb)[c4];
  float o[4];
  o[0] = fmaf(x0, w0.x, fmaf(x1, w1.x, bb.x));
  o[1] = fmaf(x0, w0.y, fmaf(x1, w1.y, bb.y));
  o[2] = fmaf(x0, w0.z, fmaf(x1, w1.z, bb.z));
  o[3] = fmaf(x0, w0.w, fmaf(x1, w1.w, bb.w));
  float4 of = { o[0], o[1], o[2], o[3] };
  ((float4*)h)[i4] = of;
  ushort hi[4], lo[4];
#pragma unroll
  for (int k = 0; k < 4; k++) split2(o[k], hi[k], lo[k]);
  uint2 ph, pl;
  ph.x = (uint)hi[0] | ((uint)hi[1] << 16);
  ph.y = (uint)hi[2] | ((uint)hi[3] << 16);
  pl.x = (uint)lo[0] | ((uint)lo[1] << 16);
  pl.y = (uint)lo[2] | ((uint)lo[3] << 16);
  ((uint2*)hhi)[i4] = ph;
  ((uint2*)hlo)[i4] = pl;
}

// ------------- weight transposes -> bf16 hi/lo [N][K] -------------
__global__ __launch_bounds__(256) void t_qkv(const float* __restrict__ Wq,
    const float* __restrict__ Wk, const float* __restrict__ Wv,
    ushort* __restrict__ dhi, ushort* __restrict__ dlo)
{
  int i = blockIdx.x * 256 + threadIdx.x;     // L*384*128 = 147456 exact
  int l = i / 49152, r = i % 49152;
  int n = r >> 7, k = r & 127;
  int which = n >> 7, hh = (n >> 4) & 7, kd = n & 15;
  const float* src = (which == 0) ? Wq : (which == 1) ? Wk : Wv;
  float w = src[l*16384 + hh*2048 + k*16 + kd];
  split2(w, dhi[i], dlo[i]);
}
__global__ __launch_bounds__(256) void t_wo(const float* __restrict__ Wo,
    ushort* __restrict__ dhi, ushort* __restrict__ dlo)
{
  int i = blockIdx.x * 256 + threadIdx.x;     // L*128*128 = 49152 exact
  int l = i / 16384, r = i % 16384;
  int n = r >> 7, k = r & 127;
  int hh = k >> 4, kd = k & 15;
  float w = Wo[l*16384 + hh*2048 + kd*128 + n];
  split2(w, dhi[i], dlo[i]);
}
__global__ __launch_bounds__(256) void t_w1(const float* __restrict__ W1,
    ushort* __restrict__ dhi, ushort* __restrict__ dlo)
{
  int i = blockIdx.x * 256 + threadIdx.x;     // L*512*128 = 196608 exact
  int l = i / 65536, r = i % 65536;
  int f = r >> 7, d = r & 127;
  float w = W1[l*65536 + d*512 + f];
  split2(w, dhi[i], dlo[i]);
}
__global__ __launch_bounds__(256) void t_w2(const float* __restrict__ W2,
    ushort* __restrict__ dhi, ushort* __restrict__ dlo)
{
  int i = blockIdx.x * 256 + threadIdx.x;     // L*128*512 = 196608 exact
  int l = i / 65536, r = i % 65536;
  int d = r >> 9, f = r & 511;
  float w = W2[l*65536 + f*128 + d];
  split2(w, dhi[i], dlo[i]);
}

// ---------------- split-bf16 MFMA GEMM (same structure as R3) ----------------
template<int K, bool BIAS, bool RELU, bool RESID, bool OUT_HL, bool STATS>
__global__ __launch_bounds__(256, 2) void gemm_mfma(
    const ushort* __restrict__ Ahi, const ushort* __restrict__ Alo,
    const ushort* __restrict__ Whi, const ushort* __restrict__ Wlo,
    const float* __restrict__ bias, const float* __restrict__ resid,
    float* __restrict__ Cf, ushort* __restrict__ Chi, ushort* __restrict__ Clo,
    float* __restrict__ psum, float* __restrict__ psq, int Ntot)
{
  __shared__ ushort AhiS[128*64];
  __shared__ ushort AloS[128*64];
  __shared__ ushort BhiS[128*64];
  __shared__ ushort BloS[128*64];
  const int t    = threadIdx.x;
  const int bm   = blockIdx.y * 128;
  const int bn   = blockIdx.x * 128;
  const int lane = t & 63;
  const int w    = t >> 6, wm = w >> 1, wn = w & 1;
  const int quad = lane >> 4, l15 = lane & 15;

  f32x4 acc[4][4];
#pragma unroll
  for (int i = 0; i < 4; i++)
#pragma unroll
    for (int j = 0; j < 4; j++) acc[i][j] = (f32x4){0.f, 0.f, 0.f, 0.f};

  const ushort* AhiB = Ahi + (size_t)bm * K;
  const ushort* AloB = Alo + (size_t)bm * K;
  const ushort* BhiB = Whi + (size_t)bn * K;
  const ushort* BloB = Wlo + (size_t)bn * K;

  for (int k0 = 0; k0 < K; k0 += 64) {
#pragma unroll
    for (int i = 0; i < 4; i++) {
      int idx = i * 256 + t;
      int row = idx >> 3, c = idx & 7;
      int k8  = c ^ (row & 7);
      size_t off = (size_t)row * K + k0 + k8 * 8;
      ((uint4*)AhiS)[idx] = *(const uint4*)(AhiB + off);
      ((uint4*)AloS)[idx] = *(const uint4*)(AloB + off);
      ((uint4*)BhiS)[idx] = *(const uint4*)(BhiB + off);
      ((uint4*)BloS)[idx] = *(const uint4*)(BloB + off);
    }
    __syncthreads();
#pragma unroll
    for (int ks = 0; ks < 2; ks++) {
      bf16x8 ah[4], al[4], bh[4], bl[4];
#pragma unroll
      for (int i = 0; i < 4; i++) {
        int row = wm * 64 + i * 16 + l15;
        int k8  = ks * 4 + quad;
        int ci  = k8 ^ (row & 7);
        ah[i] = ((const bf16x8*)AhiS)[row * 8 + ci];
        al[i] = ((const bf16x8*)AloS)[row * 8 + ci];
        int nrow = wn * 64 + i * 16 + l15;
        int cj   = k8 ^ (nrow & 7);
        bh[i] = ((const bf16x8*)BhiS)[nrow * 8 + cj];
        bl[i] = ((const bf16x8*)BloS)[nrow * 8 + cj];
      }
#pragma unroll
      for (int i = 0; i < 4; i++)
#pragma unroll
        for (int j = 0; j < 4; j++) {
          acc[i][j] = __builtin_amdgcn_mfma_f32_16x16x32_bf16(al[i], bh[j], acc[i][j], 0, 0, 0);
          acc[i][j] = __builtin_amdgcn_mfma_f32_16x16x32_bf16(ah[i], bl[j], acc[i][j], 0, 0, 0);
          acc[i][j] = __builtin_amdgcn_mfma_f32_16x16x32_bf16(ah[i], bh[j], acc[i][j], 0, 0, 0);
        }
    }
    __syncthreads();
  }

  float bv[4];
  if (BIAS) {
#pragma unroll
    for (int j = 0; j < 4; j++) bv[j] = bias[bn + wn*64 + j*16 + l15];
  }
  float sj[4] = {0.f,0.f,0.f,0.f}, qj[4] = {0.f,0.f,0.f,0.f};
#pragma unroll
  for (int i = 0; i < 4; i++) {
#pragma unroll
    for (int r = 0; r < 4; r++) {
      int row = bm + wm*64 + i*16 + quad*4 + r;
#pragma unroll
      for (int j = 0; j < 4; j++) {
        int col = bn + wn*64 + j*16 + l15;
        float v = acc[i][j][r];
        if (BIAS)  v += bv[j];
        if (RELU)  v = fmaxf(v, 0.f);
        if (RESID) v += resid[(size_t)row * Ntot + col];
        if (OUT_HL) {
          ushort hi, lo;
          split2(v, hi, lo);
          Chi[(size_t)row * Ntot + col] = hi;
          Clo[(size_t)row * Ntot + col] = lo;
        } else {
          Cf[(size_t)row * Ntot + col] = v;
        }
        if (STATS) { sj[j] += v; qj[j] = fmaf(v, v, qj[j]); }
      }
    }
  }
  if (STATS) {
#pragma unroll
    for (int j = 0; j < 4; j++) {
      sj[j] += __shfl_xor(sj[j], 16); sj[j] += __shfl_xor(sj[j], 32);
      qj[j] += __shfl_xor(qj[j], 16); qj[j] += __shfl_xor(qj[j], 32);
    }
    float* ssum = (float*)AhiS;
    float* ssq  = ssum + 128;
    if (t < 128) { ssum[t] = 0.f; ssq[t] = 0.f; }
    __syncthreads();
    if (quad == 0) {
#pragma unroll
      for (int j = 0; j < 4; j++) {
        int col = wn*64 + j*16 + l15;
        atomicAdd(&ssum[col], sj[j]);
        atomicAdd(&ssq[col],  qj[j]);
      }
    }
    __syncthreads();
    if (t < 128) {
      psum[blockIdx.y * 128 + t] = ssum[t];
      psq [blockIdx.y * 128 + t] = ssq[t];
    }
  }
}

// ---------------- MFMA flash attention: one block per (b, head) ----------------
// qkv given as hi/lo bf16 [row][384] (Q:0-127, K:128-255, V:256-383).
// Scores via hi/lo trick: MFMA1 A=[Qhi|Qlo] B=[Khi|Khi], MFMA2 A=[Qhi|0] B=[Klo|..].
// P (bf16) round-trips through wave-private LDS to reach A-layout; PV against
// transposed V (hi+lo) staged in LDS.
#define PSTR 232   // bf16 stride: 464B rows (16B aligned), 116 dwords (%32=20 -> 2-way max)
#define KVSTR 40   // bf16 stride: 80B rows, cols 0-15 Khi, 16-31 Klo

__global__ __launch_bounds__(256) void attn_kernel(
    const ushort* __restrict__ Qhi, const ushort* __restrict__ Qlo,
    ushort* __restrict__ Ohi, ushort* __restrict__ Olo)
{
  __shared__ ushort KV[208 * KVSTR];      // keys 0..207 (200..207 zero)
  __shared__ ushort Vt[32 * PSTR];        // rows 0-15: Vt_hi[dim][key], 16-31: Vt_lo
  __shared__ ushort Pb[4][16 * PSTR];     // wave-private P, cols 208..223 zero
  const int b  = blockIdx.x >> 3;
  const int hh = blockIdx.x & 7;
  const int t  = threadIdx.x;
  const int w  = t >> 6, lane = t & 63;
  const int quad = lane >> 4, l15 = lane & 15;
  const size_t rowbase = (size_t)(b * N_) * 384;

  // ---- stage K hi/lo ----
  for (int i = t; i < 400; i += 256) {
    int key = i >> 1, g = (i & 1) * 8;
    uint4 vh = *(const uint4*)(Qhi + rowbase + key*384 + 128 + hh*16 + g);
    uint4 vl = *(const uint4*)(Qlo + rowbase + key*384 + 128 + hh*16 + g);
    *(uint4*)&KV[key*KVSTR + g]      = vh;
    *(uint4*)&KV[key*KVSTR + 16 + g] = vl;
  }
  { // zero keys 200..207 (hi+lo)
    int i = t;               // 256 exact
    int key = 200 + (i >> 5), c = i & 31;
    KV[key*KVSTR + c] = 0;
  }
  // ---- stage V transposed, hi/lo ----
  for (int i = t; i < 400; i += 256) {
    int key = i >> 1, g = (i & 1) * 8;
    uint4 vh = *(const uint4*)(Qhi + rowbase + key*384 + 256 + hh*16 + g);
    uint4 vl = *(const uint4*)(Qlo + rowbase + key*384 + 256 + hh*16 + g);
    const ushort* ph = (const ushort*)&vh;
    const ushort* pl = (const ushort*)&vl;
#pragma unroll
    for (int j = 0; j < 8; j++) {
      Vt[(g + j) * PSTR + key]        = ph[j];
      Vt[(16 + g + j) * PSTR + key]   = pl[j];
    }
  }
  for (int i = t; i < 512; i += 256) {    // zero Vt cols 208..223
    int r = i >> 4, c = 208 + (i & 15);
    Vt[r*PSTR + c] = 0;
  }
  for (int i = t; i < 1024; i += 256) {   // zero Pb cols 208..223
    int ww = i >> 8, r = (i >> 4) & 15, c = 208 + (i & 15);
    Pb[ww][r*PSTR + c] = 0;
  }
  __syncthreads();

  union B8 { uint4 u; bf16x8 b; };
  B8 z8; z8.u.x = z8.u.y = z8.u.z = z8.u.w = 0;
  const f32x4 z4 = {0.f, 0.f, 0.f, 0.f};
  ushort* Pw = Pb[w];

  for (int rt = w; rt < 13; rt += 4) {
    // ---- A fragments (queries rt*16+l15) ----
    int q  = rt * 16 + l15;
    int qr = (q < N_) ? q : (N_ - 1);
    B8 h8, l8;
    h8.u = *(const uint4*)(Qhi + rowbase + qr*384 + hh*16 + (quad & 1) * 8);
    l8.u = *(const uint4*)(Qlo + rowbase + qr*384 + hh*16 + (quad & 1) * 8);
    bf16x8 a1 = (quad < 2) ? h8.b : l8.b;   // [Qhi | Qlo]
    bf16x8 a2 = (quad < 2) ? h8.b : z8.b;   // [Qhi | 0]

    // ---- scores: 13 column tiles ----
    f32x4 s[13];
#pragma unroll
    for (int ct = 0; ct < 13; ct++) {
      const bf16x8 bh = *(const bf16x8*)&KV[(ct*16 + l15) * KVSTR + (quad & 1) * 8];
      const bf16x8 bl = *(const bf16x8*)&KV[(ct*16 + l15) * KVSTR + 16 + (quad & 1) * 8];
      f32x4 acc = __builtin_amdgcn_mfma_f32_16x16x32_bf16(a2, bl, z4, 0, 0, 0);
      s[ct] = __builtin_amdgcn_mfma_f32_16x16x32_bf16(a1, bh, acc, 0, 0, 0);
    }
    // mask invalid keys 200..207 (tile 12, cols l15>=8)
    if (l15 >= 8) { s[12][0] = s[12][1] = s[12][2] = s[12][3] = -3e38f; }

    // ---- row max ----
    f32x4 mx = s[0];
#pragma unroll
    for (int ct = 1; ct < 13; ct++)
#pragma unroll
      for (int r = 0; r < 4; r++) mx[r] = fmaxf(mx[r], s[ct][r]);
#pragma unroll
    for (int d = 1; d < 16; d <<= 1)
#pragma unroll
      for (int r = 0; r < 4; r++) mx[r] = fmaxf(mx[r], __shfl_xor(mx[r], d));

    // ---- p = exp((s-mx)/4), write bf16 P to wave-private LDS ----
    f32x4 lsum = z4;
#pragma unroll
    for (int ct = 0; ct < 13; ct++) {
      f32x4 ps;
#pragma unroll
      for (int r = 0; r < 4; r++) {
        float p = __expf((s[ct][r] - mx[r]) * 0.25f);
        lsum[r] += p;
        ps[r] = p;
      }
#pragma unroll
      for (int r = 0; r < 4; r++) {
        float other = __shfl_xor(ps[r], 1);
        if ((l15 & 1) == 0) {
          uint u = (uint)f2bf(ps[r]) | ((uint)f2bf(other) << 16);
          ((uint*)Pw)[(quad*4 + r) * (PSTR/2) + ct*8 + (l15 >> 1)] = u;
        }
      }
    }
#pragma unroll
    for (int d = 1; d < 16; d <<= 1)
#pragma unroll
      for (int r = 0; r < 4; r++) lsum[r] += __shfl_xor(lsum[r], d);

    // ---- PV: O[16q x 16d] = P @ (Vhi + Vlo) ----
    f32x4 o = z4;
#pragma unroll
    for (int kt = 0; kt < 7; kt++) {
      const bf16x8 pa = *(const bf16x8*)&Pw[l15 * PSTR + kt*32 + quad*8];
      const bf16x8 vh = *(const bf16x8*)&Vt[l15 * PSTR + kt*32 + quad*8];
      const bf16x8 vl = *(const bf16x8*)&Vt[(16 + l15) * PSTR + kt*32 + quad*8];
      o = __builtin_amdgcn_mfma_f32_16x16x32_bf16(pa, vh, o, 0, 0, 0);
      o = __builtin_amdgcn_mfma_f32_16x16x32_bf16(pa, vl, o, 0, 0, 0);
    }

    // ---- store (C-layout: row=query quad*4+r, col=dim l15) ----
#pragma unroll
    for (int r = 0; r < 4; r++) {
      int qq = rt*16 + quad*4 + r;
      if (qq < N_) {
        float val = o[r] / lsum[r];
        ushort hi, lo;
        split2(val, hi, lo);
        size_t oa = ((size_t)(b * N_ + qq)) * 128 + hh*16 + l15;
        Ohi[oa] = hi;
        Olo[oa] = lo;
      }
    }
  }
}

// ---------------- BN finalize (reduce 400 partials) ----------------
__global__ __launch_bounds__(128) void bn_finalize(const float* __restrict__ psum,
    const float* __restrict__ psq, const float* __restrict__ g,
    const float* __restrict__ bta, float* __restrict__ scale, float* __restrict__ shift)
{
  int c = threadIdx.x;
  float s = 0.f, q = 0.f;
  for (int i = 0; i < 400; i++) { s += psum[i*128 + c]; q += psq[i*128 + c]; }
  const float invM = 1.f / 51200.f;
  float m  = s * invM;
  float v  = fmaf(q, invM, -m * m);
  float r  = rsqrtf(v + 1e-5f);
  float sc = r * g[c];
  scale[c] = sc;
  shift[c] = fmaf(-m, sc, bta[c]);
}

// ---------------- BN apply: fp32 out + hi/lo bf16 ----------------
__global__ __launch_bounds__(256) void bn_apply(const float* __restrict__ in,
    const float* __restrict__ scale, const float* __restrict__ shift,
    float* __restrict__ outf, ushort* __restrict__ outhi, ushort* __restrict__ outlo)
{
  int i4 = blockIdx.x * 256 + threadIdx.x;   // ROWS*32 exact
  int c4 = i4 & 31;
  float4 v  = ((const float4*)in)[i4];
  float4 sc = ((const float4*)scale)[c4];
  float4 sh = ((const float4*)shift)[c4];
  float o[4];
  o[0] = fmaf(v.x, sc.x, sh.x);
  o[1] = fmaf(v.y, sc.y, sh.y);
  o[2] = fmaf(v.z, sc.z, sh.z);
  o[3] = fmaf(v.w, sc.w, sh.w);
  float4 of = { o[0], o[1], o[2], o[3] };
  ((float4*)outf)[i4] = of;
  ushort hi[4], lo[4];
#pragma unroll
  for (int k = 0; k < 4; k++) split2(o[k], hi[k], lo[k]);
  uint2 ph, pl;
  ph.x = (uint)hi[0] | ((uint)hi[1] << 16);
  ph.y = (uint)hi[2] | ((uint)hi[3] << 16);
  pl.x = (uint)lo[0] | ((uint)lo[1] << 16);
  pl.y = (uint)lo[2] | ((uint)lo[3] << 16);
  ((uint2*)outhi)[i4] = ph;
  ((uint2*)outlo)[i4] = pl;
}

// ---------------- final mean over N ----------------
__global__ __launch_bounds__(128) void mean_kernel(const float* __restrict__ h,
                                                   float* __restrict__ out)
{
  int b = blockIdx.x, d = threadIdx.x;
  const float* p = h + (size_t)b * N_ * D_ + d;
  float s = 0.f;
  for (int n = 0; n < N_; n++) s += p[n * D_];
  out[b * D_ + d] = s * (1.f / N_);
}

extern "C" void kernel_launch(void* const* d_in, const int* in_sizes, int n_in,
                              void* d_out, int out_size, void* d_ws, size_t ws_size,
                              hipStream_t stream)
{
  const float* x    = (const float*)d_in[0];
  const float* Wemb = (const float*)d_in[1];
  const float* bemb = (const float*)d_in[2];
  const float* Wq   = (const float*)d_in[3];
  const float* Wk   = (const float*)d_in[4];
  const float* Wv   = (const float*)d_in[5];
  const float* Wo   = (const float*)d_in[6];
  const float* bn1g = (const float*)d_in[7];
  const float* bn1b = (const float*)d_in[8];
  const float* W1   = (const float*)d_in[9];
  const float* b1   = (const float*)d_in[10];
  const float* W2   = (const float*)d_in[11];
  const float* b2   = (const float*)d_in[12];
  const float* bn2g = (const float*)d_in[13];
  const float* bn2b = (const float*)d_in[14];
  float* out = (float*)d_out;

  // residual stream h lives in d_out[0:BND]
  float* h = out;

  char* wsb = (char*)d_ws;
  ushort* h_hi  = (ushort*)wsb;                     // 13,107,200 B
  ushort* h_lo  = (ushort*)(wsb + 13107200);        // 13,107,200 B
  char*   phase = wsb + 26214400;                   // 104,857,600 B union
  ushort* qkv_hi = (ushort*)phase;                  //   attn: 39,321,600 B
  ushort* qkv_lo = (ushort*)(phase + 39321600);     //   attn: 39,321,600 B
  ushort* hd_hi  = (ushort*)(phase + 78643200);     //   attn: 13,107,200 B
  ushort* hd_lo  = (ushort*)(phase + 91750400);     //   attn: 13,107,200 B
  ushort* hid_hi = (ushort*)phase;                  //   ffn: 52,428,800 B
  ushort* hid_lo = (ushort*)(phase + 52428800);     //   ffn: 52,428,800 B
  char*   wp    = wsb + 131072000;
  ushort* qkvT_hi = (ushort*)wp;                    // 294,912 B
  ushort* qkvT_lo = (ushort*)(wp + 294912);
  ushort* woT_hi  = (ushort*)(wp + 589824);         // 98,304 B
  ushort* woT_lo  = (ushort*)(wp + 688128);
  ushort* w1T_hi  = (ushort*)(wp + 786432);         // 393,216 B
  ushort* w1T_lo  = (ushort*)(wp + 1179648);
  ushort* w2T_hi  = (ushort*)(wp + 1572864);        // 393,216 B
  ushort* w2T_lo  = (ushort*)(wp + 1966080);
  float*  psum    = (float*)(wp + 2359296);         // 204,800 B
  float*  psq     = (float*)(wp + 2564096);         // 204,800 B
  float*  scale   = (float*)(wp + 2768896);
  float*  shift   = (float*)(wp + 2769408);

  embed_kernel<<<6400, 256, 0, stream>>>(x, Wemb, bemb, h, h_hi, h_lo);
  t_qkv<<<576, 256, 0, stream>>>(Wq, Wk, Wv, qkvT_hi, qkvT_lo);
  t_wo <<<192, 256, 0, stream>>>(Wo, woT_hi, woT_lo);
  t_w1 <<<768, 256, 0, stream>>>(W1, w1T_hi, w1T_lo);
  t_w2 <<<768, 256, 0, stream>>>(W2, w2T_hi, w2T_lo);

  for (int l = 0; l < L_; l++) {
    const ushort* qkvh = qkvT_hi + l * 49152;
    const ushort* qkvl = qkvT_lo + l * 49152;
    const ushort* woh  = woT_hi  + l * 16384;
    const ushort* wol  = woT_lo  + l * 16384;
    const ushort* w1h  = w1T_hi  + l * 65536;
    const ushort* w1l  = w1T_lo  + l * 65536;
    const ushort* w2h  = w2T_hi  + l * 65536;
    const ushort* w2l  = w2T_lo  + l * 65536;

    // fused QKV projection -> qkv hi/lo bf16 [rows][384]
    gemm_mfma<128, false, false, false, true, false><<<dim3(3, 400), 256, 0, stream>>>(
        h_hi, h_lo, qkvh, qkvl, nullptr, nullptr, nullptr, qkv_hi, qkv_lo, nullptr, nullptr, 384);
    // MFMA flash attention -> heads hi/lo
    attn_kernel<<<B_ * H_, 256, 0, stream>>>(qkv_hi, qkv_lo, hd_hi, hd_lo);
    // out-proj + residual -> h fp32, + BN1 partial stats
    gemm_mfma<128, false, false, true, false, true><<<dim3(1, 400), 256, 0, stream>>>(
        hd_hi, hd_lo, woh, wol, nullptr, h, h, nullptr, nullptr, psum, psq, 128);
    bn_finalize<<<1, 128, 0, stream>>>(psum, psq, bn1g + l*128, bn1b + l*128, scale, shift);
    bn_apply<<<6400, 256, 0, stream>>>(h, scale, shift, h, h_hi, h_lo);
    // FFN1 + bias + relu -> hidden hi/lo
    gemm_mfma<128, true, true, false, true, false><<<dim3(4, 400), 256, 0, stream>>>(
        h_hi, h_lo, w1h, w1l, b1 + l*512, nullptr, nullptr, hid_hi, hid_lo, nullptr, nullptr, 512);
    // FFN2 + bias + residual -> h fp32, + BN2 partial stats
    gemm_mfma<512, true, false, true, false, true><<<dim3(1, 400), 256, 0, stream>>>(
        hid_hi, hid_lo, w2h, w2l, b2 + l*128, h, h, nullptr, nullptr, psum, psq, 128);
    bn_finalize<<<1, 128, 0, stream>>>(psum, psq, bn2g + l*128, bn2b + l*128, scale, shift);
    bn_apply<<<6400, 256, 0, stream>>>(h, scale, shift, h, h_hi, h_lo);
  }

  mean_kernel<<<B_, 128, 0, stream>>>(out, out + BND);
}